// Round 9
// baseline (201.766 us; speedup 1.0000x reference)
//
#include <hip/hip_runtime.h>
#include <hip/hip_cooperative_groups.h>

namespace cg = cooperative_groups;

// EWMA scan y_t = (1-a)*y_{t-1} + a*x_t, y_{-1} = first_offset.
// Fused cooperative kernel = R1's exact 3-phase math (best measured: 74us)
// with the two inter-kernel launch gaps replaced by grid.sync().
//   A: per-chunk zero-init local scan -> zend (per-chunk aggregates)
//   B: inter-chunk scan, one wave per column (Kogge-Stone over 64 lanes)
//   C: recompute local scan, add decay^(i+1)*carry, store out + last row.
// TCH=64 (every smaller TCH measured worse: R4/R7/R8); plain loads/stores
// (nt hints measured harmful: R4/R6).

#define LT   32768
#define DC   1024
#define TCH  64
#define CCH  (LT / TCH)       // 512 chunks = 512 blocks (2/CU, co-resident)
#define TPB  256
#define D4   (DC / 4)         // 256 float4 per row

typedef float nf4 __attribute__((ext_vector_type(4)));

__global__ __launch_bounds__(TPB, 2)
void ewma_fused(const nf4* __restrict__ data4,
                const float* __restrict__ first,
                const float* __restrict__ alpha_p,
                nf4* __restrict__ out4,
                nf4* __restrict__ zend4,
                float* __restrict__ carry) {
    cg::grid_group grid = cg::this_grid();
    const float alpha = alpha_p[0];
    const float decay = 1.0f - alpha;
    const int tid = threadIdx.x;
    const int c = blockIdx.x;      // chunk index

    // ---------------- Stage A: local zero-init scan, publish aggregate ----
    {
        const nf4* p = data4 + (size_t)c * TCH * D4 + tid;
        float z0 = 0.f, z1 = 0.f, z2 = 0.f, z3 = 0.f;
#pragma unroll 8
        for (int i = 0; i < TCH; ++i) {
            nf4 x = p[(size_t)i * D4];
            z0 = fmaf(decay, z0, alpha * x.x);
            z1 = fmaf(decay, z1, alpha * x.y);
            z2 = fmaf(decay, z2, alpha * x.z);
            z3 = fmaf(decay, z3, alpha * x.w);
        }
        nf4 zv; zv.x = z0; zv.y = z1; zv.z = z2; zv.w = z3;
        zend4[(size_t)c * D4 + tid] = zv;
    }

    grid.sync();

    // ---------------- Stage B: inter-chunk scan (blocks 0..255) -----------
    // Wave w of block b owns column d = b*4 + w; lane l owns chunks
    // [l*CPL, (l+1)*CPL), CPL = 8. S_c = r*S_{c-1} + e_c, r = decay^TCH.
    if (c < DC / 4) {
        const int lane = tid & 63;
        const int w = tid >> 6;
        const int d = c * 4 + w;
        float r = decay;             // decay^64 via 6 squarings
        r *= r; r *= r; r *= r; r *= r; r *= r; r *= r;
        constexpr int CPL = CCH / 64;   // 8

        const float* zend = (const float*)zend4;
        float e[CPL];
#pragma unroll
        for (int j = 0; j < CPL; ++j)
            e[j] = zend[(size_t)(lane * CPL + j) * DC + d];

        float A = 0.f;
#pragma unroll
        for (int j = 0; j < CPL; ++j) A = fmaf(r, A, e[j]);

        float q = r;                 // r^CPL, CPL=8 -> 3 squarings
        q *= q; q *= q; q *= q;

        float y = A;
        float pq = q;
#pragma unroll
        for (int o = 1; o < 64; o <<= 1) {
            float prev = __shfl_up(y, o, 64);
            if (lane >= o) y = fmaf(pq, prev, y);
            pq = pq * pq;
        }
        float excl = __shfl_up(y, 1, 64);
        if (lane == 0) excl = 0.f;

        float qpow = 1.f;            // q^lane
        {
            float base = q;
            int e2 = lane;
            while (e2) { if (e2 & 1) qpow *= base; base *= base; e2 >>= 1; }
        }
        float S = fmaf(qpow, first[d], excl);   // carry entering lane's first chunk

#pragma unroll
        for (int j = 0; j < CPL; ++j) {
            const int cc = lane * CPL + j;
            carry[(size_t)cc * DC + d] = S;
            S = fmaf(r, S, e[j]);
        }
    }

    grid.sync();

    // ---------------- Stage C: recompute + correct + store out ------------
    {
        const nf4 cin = ((const nf4*)carry)[(size_t)c * D4 + tid];
        const nf4* p = data4 + (size_t)c * TCH * D4 + tid;
        nf4* o = out4 + (size_t)c * TCH * D4 + tid;
        float z0 = 0.f, z1 = 0.f, z2 = 0.f, z3 = 0.f, pw = 1.f;
#pragma unroll 8
        for (int i = 0; i < TCH; ++i) {
            nf4 x = p[(size_t)i * D4];
            z0 = fmaf(decay, z0, alpha * x.x);
            z1 = fmaf(decay, z1, alpha * x.y);
            z2 = fmaf(decay, z2, alpha * x.z);
            z3 = fmaf(decay, z3, alpha * x.w);
            pw *= decay;
            nf4 yv;
            yv.x = fmaf(pw, cin.x, z0);
            yv.y = fmaf(pw, cin.y, z1);
            yv.z = fmaf(pw, cin.z, z2);
            yv.w = fmaf(pw, cin.w, z3);
            o[(size_t)i * D4] = yv;
        }
        if (c == CCH - 1) {
            nf4 yl;
            yl.x = fmaf(pw, cin.x, z0);
            yl.y = fmaf(pw, cin.y, z1);
            yl.z = fmaf(pw, cin.z, z2);
            yl.w = fmaf(pw, cin.w, z3);
            ((nf4*)(((float*)out4) + (size_t)LT * DC))[tid] = yl;
        }
    }
}

extern "C" void kernel_launch(void* const* d_in, const int* in_sizes, int n_in,
                              void* d_out, int out_size, void* d_ws, size_t ws_size,
                              hipStream_t stream) {
    const float* data    = (const float*)d_in[0];
    const float* first   = (const float*)d_in[1];
    const float* alpha_p = (const float*)d_in[2];
    float* out = (float*)d_out;

    float* zend  = (float*)d_ws;              // CCH*DC floats = 2 MB
    float* carry = zend + (size_t)CCH * DC;   // CCH*DC floats = 2 MB

    const nf4* data4 = (const nf4*)data;
    nf4* out4 = (nf4*)out;
    nf4* zend4 = (nf4*)zend;

    void* args[] = { (void*)&data4, (void*)&first, (void*)&alpha_p,
                     (void*)&out4, (void*)&zend4, (void*)&carry };
    hipLaunchCooperativeKernel((const void*)ewma_fused,
                               dim3(CCH), dim3(TPB), args, 0, stream);
}